// Round 1
// baseline (1022.785 us; speedup 1.0000x reference)
//
#include <hip/hip_runtime.h>
#include <cstdint>
#include <cstddef>

#define N_IN  700
#define N_HID 512
#define N_OUT 20
#define BB    256
#define TT    100
#define NK    (BB*TT)   // 25600

__device__ __constant__ const float TAU   = 0.6f;
__device__ __constant__ const float TAU_O = 0.6f;
__device__ __constant__ const float THR   = 0.6f;
__device__ __constant__ const float GAM   = 0.3f;

// ---------------- prep ----------------
__global__ void k_prep_t1(const float* __restrict__ W1, float* __restrict__ W1T) {
  int g = blockIdx.x*256 + threadIdx.x;           // g = i*512 + r
  if (g < N_IN*N_HID) {
    int i = g >> 9, r = g & 511;
    W1T[g] = W1[r*N_IN + i];
  }
}
__global__ void k_prep_t2(const float* __restrict__ Wr, float* __restrict__ WRT) {
  int g = blockIdx.x*256 + threadIdx.x;           // g = j*512 + r
  if (g < N_HID*N_HID) {
    int j = g >> 9, r = g & 511;
    WRT[g] = Wr[r*N_HID + j];
  }
}
__global__ void k_prep_sums(const float* __restrict__ Wr, const float* __restrict__ Wo,
                            float* __restrict__ Srow, float* __restrict__ SOs,
                            unsigned int* __restrict__ flags) {
  int g = blockIdx.x*256 + threadIdx.x;           // grid covers NK threads
  if (g < N_HID) {
    float s = 0.f;
    for (int j = 0; j < N_HID; ++j) s += Wr[g*N_HID + j];
    Srow[g] = s;
  } else if (g < N_HID + N_OUT) {
    int o = g - N_HID;
    float s = 0.f;
    for (int r = 0; r < N_HID; ++r) s += Wo[o*N_HID + r];
    SOs[o] = s;
  }
  if (g < NK) flags[g] = 0u;
}

// ---------------- phase A: IN[k][r] = sum_{i active} W1T[i][r]  (exact fp32) ----------------
__global__ __launch_bounds__(256) void k_inproj(const float* __restrict__ x,
                                                const float* __restrict__ W1T,
                                                float* __restrict__ INL) {
  const int w = threadIdx.x >> 6, lane = threadIdx.x & 63;
  __shared__ int lists[4][704];
  const int k = blockIdx.x*4 + w;                 // 6400 blocks * 4 waves = 25600
  const float* xrow = x + (size_t)k * N_IN;
  int cnt = 0;
  for (int i0 = 0; i0 < N_IN; i0 += 64) {
    const int i = i0 + lane;
    const int act = (i < N_IN) && (xrow[i] != 0.f);
    const unsigned long long m = __ballot(act != 0);
    if (act) lists[w][cnt + __popcll(m & ((1ULL << lane) - 1ULL))] = i;
    cnt += (int)__popcll(m);
  }
  float a0=0.f,a1=0.f,a2=0.f,a3=0.f,b0=0.f,b1=0.f,b2=0.f,b3=0.f;
  for (int it = 0; it < cnt; ++it) {
    const int j = lists[w][it];
    const float4 va = *(const float4*)(W1T + (size_t)j*N_HID + 4*lane);
    const float4 vb = *(const float4*)(W1T + (size_t)j*N_HID + 256 + 4*lane);
    a0 += va.x; a1 += va.y; a2 += va.z; a3 += va.w;
    b0 += vb.x; b1 += vb.y; b2 += vb.z; b3 += vb.w;
  }
  float4* op = (float4*)(INL + (size_t)k*N_HID);
  op[lane]      = make_float4(a0,a1,a2,a3);
  op[64 + lane] = make_float4(b0,b1,b2,b3);
}

// ---------------- phase B: sequential scan, one batch row per block ----------------
__global__ __launch_bounds__(256) void k_scan(
    float* __restrict__ INL,                  // [NK][512] in: IN, out: L (overwritten in place)
    const float* __restrict__ label,          // [NK][20]
    const float* __restrict__ Wo,             // [20][512]
    const float* __restrict__ WRT,            // [512][512] j-major
    const float* __restrict__ Srow,           // [512]
    const float* __restrict__ SOs,            // [20]
    unsigned long long* __restrict__ hsbits,  // [NK][8]
    float* __restrict__ outs,                 // [NK][20] -> d_out
    float* __restrict__ pgo)                  // [256][20][512]
{
  const int b = blockIdx.x, tid = threadIdx.x;
  const int lane = tid & 63, w = tid >> 6;
  __shared__ float sWo[N_OUT*N_HID];          // 40 KB
  __shared__ float errs[N_OUT];
  __shared__ int   list[N_HID];
  __shared__ unsigned long long masks[8];
  __shared__ int   offs[8];
  __shared__ int   cnt_s, mode_s;
  __shared__ float part[N_OUT][13];

  for (int idx = tid; idx < N_OUT*N_HID; idx += 256) sWo[idx] = Wo[idx];

  float hm0 = 0.f, hm1 = 0.f;
  int   hs0 = 0,   hs1 = 0;
  float om = 0.f;  int osb = 0;
  float tout0 = 0.f, tout1 = 0.f;
  float go0[N_OUT], go1[N_OUT];
  #pragma unroll
  for (int o = 0; o < N_OUT; ++o) { go0[o] = 0.f; go1[o] = 0.f; }
  int cnt_prev = 0, mode_prev = 0;
  __syncthreads();

  for (int t = 0; t < TT; ++t) {
    const int k = b*TT + t;
    const float in0 = INL[(size_t)k*N_HID + tid];
    const float in1 = INL[(size_t)k*N_HID + 256 + tid];

    // recurrent drive: active-list sum, or rowsum minus complement sum
    float s0 = 0.f, s1 = 0.f;
    for (int it = 0; it < cnt_prev; ++it) {
      const int j = list[it];
      s0 += WRT[j*N_HID + tid];
      s1 += WRT[j*N_HID + 256 + tid];
    }
    float rec0, rec1;
    if (mode_prev == 0) { rec0 = s0; rec1 = s1; }
    else { rec0 = Srow[tid] - s0; rec1 = Srow[256 + tid] - s1; }

    const float nhm0 = TAU*hm0*(hs0 ? 0.f : 1.f) + in0 + rec0;
    const float nhm1 = TAU*hm1*(hs1 ? 0.f : 1.f) + in1 + rec1;
    const int nhs0 = (nhm0 >= THR) ? 1 : 0;
    const int nhs1 = (nhm1 >= THR) ? 1 : 0;

    const unsigned long long mA = __ballot(nhs0 != 0);
    const unsigned long long mB = __ballot(nhs1 != 0);
    if (lane == 0) { masks[w] = mA; masks[4 + w] = mB; }
    __syncthreads();
    if (tid == 0) {
      int c = 0;
      #pragma unroll
      for (int q = 0; q < 8; ++q) c += (int)__popcll(masks[q]);
      const int mode = (c <= 256) ? 0 : 1;
      int run = 0;
      #pragma unroll
      for (int q = 0; q < 8; ++q) {
        offs[q] = run;
        const int pc = (int)__popcll(masks[q]);
        run += (mode == 0) ? pc : (64 - pc);
      }
      cnt_s = run; mode_s = mode;
    }
    if (tid < 8) hsbits[(size_t)k*8 + tid] = masks[tid];
    __syncthreads();
    const int cnt = cnt_s, mode = mode_s;
    {
      const unsigned long long below = (1ULL << lane) - 1ULL;
      const unsigned long long sm0 = mode ? ~mA : mA;
      const unsigned long long sm1 = mode ? ~mB : mB;
      const int sel0 = mode ? !nhs0 : nhs0;
      const int sel1 = mode ? !nhs1 : nhs1;
      if (sel0) list[offs[w]     + (int)__popcll(sm0 & below)] = tid;
      if (sel1) list[offs[4 + w] + (int)__popcll(sm1 & below)] = tid + 256;
    }
    __syncthreads();

    // output-neuron drive
    if (tid < 240) {
      const int o = tid / 12, c2 = tid % 12;
      float s = 0.f;
      for (int it = c2; it < cnt; it += 12) s += sWo[o*N_HID + list[it]];
      part[o][c2] = s;
    }
    __syncthreads();
    if (tid < N_OUT) {
      float drive = 0.f;
      #pragma unroll
      for (int c2 = 0; c2 < 12; ++c2) drive += part[tid][c2];
      if (mode) drive = SOs[tid] - drive;
      om = TAU*om*(osb ? 0.f : 1.f) + drive;
      const int nos = (om >= THR) ? 1 : 0;
      const float osf = nos ? 1.f : 0.f;
      errs[tid] = osf - label[(size_t)k*N_OUT + tid];
      outs[(size_t)k*N_OUT + tid] = osf;
      osb = nos;
    }
    __syncthreads();

    // L = (err @ W_out) * h'(hm); store into INL (in place); go partial accum
    float d0 = 0.f, d1 = 0.f;
    #pragma unroll
    for (int o = 0; o < N_OUT; ++o) {
      const float e = errs[o];
      d0 += e * sWo[o*N_HID + tid];
      d1 += e * sWo[o*N_HID + 256 + tid];
    }
    const float a0f = fabsf(nhm0 - THR) / THR;
    const float a1f = fabsf(nhm1 - THR) / THR;
    const float ht0 = GAM * fmaxf(0.f, 1.f - a0f);
    const float ht1 = GAM * fmaxf(0.f, 1.f - a1f);
    INL[(size_t)k*N_HID + tid]       = d0 * ht0;
    INL[(size_t)k*N_HID + 256 + tid] = d1 * ht1;

    tout0 = TAU_O*tout0 + (nhs0 ? 1.f : 0.f);
    tout1 = TAU_O*tout1 + (nhs1 ? 1.f : 0.f);
    #pragma unroll
    for (int o = 0; o < N_OUT; ++o) {
      const float e = errs[o];
      go0[o] += e * tout0;
      go1[o] += e * tout1;
    }

    hm0 = nhm0; hm1 = nhm1; hs0 = nhs0; hs1 = nhs1;
    cnt_prev = cnt; mode_prev = mode;
    __syncthreads();
  }
  #pragma unroll
  for (int o = 0; o < N_OUT; ++o) {
    pgo[((size_t)b*N_OUT + o)*N_HID + tid]       = go0[o];
    pgo[((size_t)b*N_OUT + o)*N_HID + 256 + tid] = go1[o];
  }
}

// ---------------- phase C: reverse filter M_s = L_s + tau*M_{s+1}, in place; nonzero flags ----------------
__global__ void k_mfilter(float* __restrict__ L, unsigned int* __restrict__ flags) {
  const int g = blockIdx.x*256 + threadIdx.x;   // 512 blocks -> (b, r)
  const int b = g >> 9, r = g & 511;
  float m = 0.f;
  for (int t = TT - 1; t >= 0; --t) {
    const size_t idx = ((size_t)(b*TT + t))*N_HID + r;
    const float v = L[idx] + TAU*m;
    L[idx] = v;
    m = v;
    if (v != 0.f) flags[b*TT + t] = 1u;         // benign race, deterministic value
  }
}

// ---------------- phase D: gf = 0.1 * sum_k M[k,:]^T x[k,:]  over flagged k ----------------
__global__ __launch_bounds__(256) void k_gf(const float* __restrict__ M, const float* __restrict__ x,
                                            const unsigned int* __restrict__ flags,
                                            float* __restrict__ gf) {
  const int lane = threadIdx.x & 63, w = threadIdx.x >> 6;
  const int r  = blockIdx.x*64 + lane;
  const int i0 = blockIdx.y*64 + w*16;
  float acc[16];
  #pragma unroll
  for (int ii = 0; ii < 16; ++ii) acc[ii] = 0.f;
  int xi = i0 + (lane & 15); if (xi > N_IN - 1) xi = N_IN - 1;
  for (int k0 = 0; k0 < NK; k0 += 64) {
    const unsigned int f = flags[k0 + lane];
    unsigned long long msk = __ballot(f != 0u);
    while (msk) {
      const int j = __ffsll((long long)msk) - 1;
      msk &= (msk - 1ULL);
      const int k = k0 + j;
      const float mv = M[(size_t)k*N_HID + r];
      const float xv = x[(size_t)k*N_IN + xi];
      #pragma unroll
      for (int ii = 0; ii < 16; ++ii) acc[ii] += mv * __shfl(xv, ii);
    }
  }
  #pragma unroll
  for (int ii = 0; ii < 16; ++ii) {
    const int i = i0 + ii;
    if (i < N_IN) gf[(size_t)r*N_IN + i] = 0.1f*acc[ii];
  }
}

// ---------------- phase D: gr = 0.1 * sum_k M[k,:]^T hs[k,:] over flagged k ----------------
__global__ __launch_bounds__(256) void k_gr(const float* __restrict__ M,
                                            const unsigned long long* __restrict__ hsbits,
                                            const unsigned int* __restrict__ flags,
                                            float* __restrict__ gr) {
  const int lane = threadIdx.x & 63, w = threadIdx.x >> 6;
  const int r  = blockIdx.x*64 + lane;
  const int h0 = blockIdx.y*64 + w*16;
  float acc[16];
  #pragma unroll
  for (int ii = 0; ii < 16; ++ii) acc[ii] = 0.f;
  for (int k0 = 0; k0 < NK; k0 += 64) {
    const unsigned int f = flags[k0 + lane];
    unsigned long long msk = __ballot(f != 0u);
    while (msk) {
      const int j = __ffsll((long long)msk) - 1;
      msk &= (msk - 1ULL);
      const int k = k0 + j;
      const float mv = M[(size_t)k*N_HID + r];
      const unsigned long long word = hsbits[(size_t)k*8 + (h0 >> 6)];
      const int sh = h0 & 63;
      #pragma unroll
      for (int ii = 0; ii < 16; ++ii)
        if ((word >> (sh + ii)) & 1ULL) acc[ii] += mv;
    }
  }
  #pragma unroll
  for (int ii = 0; ii < 16; ++ii)
    gr[(size_t)r*N_HID + h0 + ii] = 0.1f*acc[ii];
}

// ---------------- phase D: go = 0.1 * sum_b pgo[b] ----------------
__global__ void k_go(const float* __restrict__ pgo, float* __restrict__ go) {
  const int g = blockIdx.x*256 + threadIdx.x;   // 40 blocks -> 10240
  float s = 0.f;
  for (int b2 = 0; b2 < BB; ++b2) s += pgo[(size_t)b2*(N_OUT*N_HID) + g];
  go[g] = 0.1f*s;
}

extern "C" void kernel_launch(void* const* d_in, const int* in_sizes, int n_in,
                              void* d_out, int out_size, void* d_ws, size_t ws_size,
                              hipStream_t stream) {
  const float* x     = (const float*)d_in[0];
  const float* label = (const float*)d_in[1];
  const float* W1    = (const float*)d_in[2];
  const float* Wr    = (const float*)d_in[3];
  const float* Wo    = (const float*)d_in[4];

  float* out  = (float*)d_out;
  float* outs = out;                                    // [256][100][20]
  float* gf   = out + 512000;                           // [512][700]
  float* gr   = out + 512000 + 358400;                  // [512][512]
  float* go   = out + 512000 + 358400 + 262144;         // [20][512]

  char* ws = (char*)d_ws;
  size_t off = 0;
  auto alloc = [&](size_t bytes) -> char* {
    char* p = ws + off;
    off += (bytes + 255) & ~(size_t)255;
    return p;
  };
  float* INL  = (float*)alloc((size_t)NK*N_HID*sizeof(float));       // 52.4 MB (IN -> L -> M)
  float* W1T  = (float*)alloc((size_t)N_IN*N_HID*sizeof(float));     // 1.43 MB
  float* WRT  = (float*)alloc((size_t)N_HID*N_HID*sizeof(float));    // 1.05 MB
  float* Srow = (float*)alloc((size_t)N_HID*sizeof(float));
  float* SOs  = (float*)alloc((size_t)N_OUT*sizeof(float));
  unsigned long long* hsb = (unsigned long long*)alloc((size_t)NK*8*sizeof(unsigned long long)); // 1.64 MB
  unsigned int* flags = (unsigned int*)alloc((size_t)NK*sizeof(unsigned int));                   // 0.1 MB
  float* pgo  = (float*)alloc((size_t)BB*N_OUT*N_HID*sizeof(float)); // 10.5 MB

  k_prep_t1<<<(N_IN*N_HID + 255)/256, 256, 0, stream>>>(W1, W1T);
  k_prep_t2<<<(N_HID*N_HID + 255)/256, 256, 0, stream>>>(Wr, WRT);
  k_prep_sums<<<(NK + 255)/256, 256, 0, stream>>>(Wr, Wo, Srow, SOs, flags);
  k_inproj<<<NK/4, 256, 0, stream>>>(x, W1T, INL);
  k_scan<<<BB, 256, 0, stream>>>(INL, label, Wo, WRT, Srow, SOs, hsb, outs, pgo);
  k_mfilter<<<(BB*N_HID)/256, 256, 0, stream>>>(INL, flags);
  dim3 ggf(8, 11); k_gf<<<ggf, 256, 0, stream>>>(INL, x, flags, gf);
  dim3 ggr(8, 8);  k_gr<<<ggr, 256, 0, stream>>>(INL, hsb, flags, gr);
  k_go<<<(N_OUT*N_HID)/256, 256, 0, stream>>>(pgo, go);
}

// Round 2
// 1017.179 us; speedup vs baseline: 1.0055x; 1.0055x over previous
//
#include <hip/hip_runtime.h>
#include <cstdint>
#include <cstddef>

#define N_IN  700
#define N_HID 512
#define N_OUT 20
#define BB    256
#define TT    100
#define NK    (BB*TT)   // 25600

__device__ __constant__ const float TAU   = 0.6f;
__device__ __constant__ const float TAU_O = 0.6f;
__device__ __constant__ const float THR   = 0.6f;
__device__ __constant__ const float GAM   = 0.3f;

// ---------------- prep ----------------
__global__ void k_prep_t1(const float* __restrict__ W1, float* __restrict__ W1T) {
  int g = blockIdx.x*256 + threadIdx.x;           // g = i*512 + r
  if (g < N_IN*N_HID) {
    int i = g >> 9, r = g & 511;
    W1T[g] = W1[r*N_IN + i];
  }
}
__global__ void k_prep_t2(const float* __restrict__ Wr, float* __restrict__ WRT) {
  int g = blockIdx.x*256 + threadIdx.x;           // g = j*512 + r
  if (g < N_HID*N_HID) {
    int j = g >> 9, r = g & 511;
    WRT[g] = Wr[r*N_HID + j];
  }
}
__global__ void k_prep_sums(const float* __restrict__ Wr, const float* __restrict__ Wo,
                            float* __restrict__ Srow, float* __restrict__ SOs,
                            int* __restrict__ tmax) {
  int g = blockIdx.x*256 + threadIdx.x;
  if (g < N_HID) {
    float s = 0.f;
    for (int j = 0; j < N_HID; ++j) s += Wr[g*N_HID + j];
    Srow[g] = s;
  } else if (g < N_HID + N_OUT) {
    int o = g - N_HID;
    float s = 0.f;
    for (int r = 0; r < N_HID; ++r) s += Wo[o*N_HID + r];
    SOs[o] = s;
  }
  if (g < BB) tmax[g] = 0;
}

// ---------------- phase A: IN[k][r] = sum_{i active} W1T[i][r]  (exact fp32) ----------------
__global__ __launch_bounds__(256) void k_inproj(const float* __restrict__ x,
                                                const float* __restrict__ W1T,
                                                float* __restrict__ INL) {
  const int w = threadIdx.x >> 6, lane = threadIdx.x & 63;
  __shared__ int lists[4][704];
  const int k = blockIdx.x*4 + w;                 // 6400 blocks * 4 waves = 25600
  const float* xrow = x + (size_t)k * N_IN;
  int cnt = 0;
  for (int i0 = 0; i0 < N_IN; i0 += 64) {
    const int i = i0 + lane;
    const int act = (i < N_IN) && (xrow[i] != 0.f);
    const unsigned long long m = __ballot(act != 0);
    if (act) lists[w][cnt + __popcll(m & ((1ULL << lane) - 1ULL))] = i;
    cnt += (int)__popcll(m);
  }
  float a0=0.f,a1=0.f,a2=0.f,a3=0.f,b0=0.f,b1=0.f,b2=0.f,b3=0.f;
  for (int it = 0; it < cnt; ++it) {
    const int j = lists[w][it];
    const float4 va = *(const float4*)(W1T + (size_t)j*N_HID + 4*lane);
    const float4 vb = *(const float4*)(W1T + (size_t)j*N_HID + 256 + 4*lane);
    a0 += va.x; a1 += va.y; a2 += va.z; a3 += va.w;
    b0 += vb.x; b1 += vb.y; b2 += vb.z; b3 += vb.w;
  }
  float4* op = (float4*)(INL + (size_t)k*N_HID);
  op[lane]      = make_float4(a0,a1,a2,a3);
  op[64 + lane] = make_float4(b0,b1,b2,b3);
}

// ---------------- phase B: sequential scan, one batch row per block ----------------
__global__ __launch_bounds__(256) void k_scan(
    float* __restrict__ INL,                  // [NK][512] in: IN, out: L (overwritten in place)
    const float* __restrict__ label,          // [NK][20]
    const float* __restrict__ Wo,             // [20][512]
    const float* __restrict__ WRT,            // [512][512] j-major
    const float* __restrict__ Srow,           // [512]
    const float* __restrict__ SOs,            // [20]
    unsigned long long* __restrict__ hsbits,  // [NK][8]
    float* __restrict__ outs,                 // [NK][20] -> d_out
    float* __restrict__ pgo)                  // [256][20][512]
{
  const int b = blockIdx.x, tid = threadIdx.x;
  const int lane = tid & 63, w = tid >> 6;
  __shared__ float sWo[N_OUT*N_HID];          // 40 KB
  __shared__ float errs[N_OUT];
  __shared__ int   list[N_HID];
  __shared__ unsigned long long masks[8];
  __shared__ int   offs[8];
  __shared__ int   cnt_s, mode_s;
  __shared__ float part[N_OUT][13];

  for (int idx = tid; idx < N_OUT*N_HID; idx += 256) sWo[idx] = Wo[idx];

  float hm0 = 0.f, hm1 = 0.f;
  int   hs0 = 0,   hs1 = 0;
  float om = 0.f;  int osb = 0;
  float tout0 = 0.f, tout1 = 0.f;
  float go0[N_OUT], go1[N_OUT];
  #pragma unroll
  for (int o = 0; o < N_OUT; ++o) { go0[o] = 0.f; go1[o] = 0.f; }
  int cnt_prev = 0, mode_prev = 0;
  __syncthreads();

  for (int t = 0; t < TT; ++t) {
    const int k = b*TT + t;
    const float in0 = INL[(size_t)k*N_HID + tid];
    const float in1 = INL[(size_t)k*N_HID + 256 + tid];

    // recurrent drive: active-list sum, or rowsum minus complement sum
    float s0 = 0.f, s1 = 0.f;
    for (int it = 0; it < cnt_prev; ++it) {
      const int j = list[it];
      s0 += WRT[j*N_HID + tid];
      s1 += WRT[j*N_HID + 256 + tid];
    }
    float rec0, rec1;
    if (mode_prev == 0) { rec0 = s0; rec1 = s1; }
    else { rec0 = Srow[tid] - s0; rec1 = Srow[256 + tid] - s1; }

    const float nhm0 = TAU*hm0*(hs0 ? 0.f : 1.f) + in0 + rec0;
    const float nhm1 = TAU*hm1*(hs1 ? 0.f : 1.f) + in1 + rec1;
    const int nhs0 = (nhm0 >= THR) ? 1 : 0;
    const int nhs1 = (nhm1 >= THR) ? 1 : 0;

    const unsigned long long mA = __ballot(nhs0 != 0);
    const unsigned long long mB = __ballot(nhs1 != 0);
    if (lane == 0) { masks[w] = mA; masks[4 + w] = mB; }
    __syncthreads();
    if (tid == 0) {
      int c = 0;
      #pragma unroll
      for (int q = 0; q < 8; ++q) c += (int)__popcll(masks[q]);
      const int mode = (c <= 256) ? 0 : 1;
      int run = 0;
      #pragma unroll
      for (int q = 0; q < 8; ++q) {
        offs[q] = run;
        const int pc = (int)__popcll(masks[q]);
        run += (mode == 0) ? pc : (64 - pc);
      }
      cnt_s = run; mode_s = mode;
    }
    if (tid < 8) hsbits[(size_t)k*8 + tid] = masks[tid];
    __syncthreads();
    const int cnt = cnt_s, mode = mode_s;
    {
      const unsigned long long below = (1ULL << lane) - 1ULL;
      const unsigned long long sm0 = mode ? ~mA : mA;
      const unsigned long long sm1 = mode ? ~mB : mB;
      const int sel0 = mode ? !nhs0 : nhs0;
      const int sel1 = mode ? !nhs1 : nhs1;
      if (sel0) list[offs[w]     + (int)__popcll(sm0 & below)] = tid;
      if (sel1) list[offs[4 + w] + (int)__popcll(sm1 & below)] = tid + 256;
    }
    __syncthreads();

    // output-neuron drive
    if (tid < 240) {
      const int o = tid / 12, c2 = tid % 12;
      float s = 0.f;
      for (int it = c2; it < cnt; it += 12) s += sWo[o*N_HID + list[it]];
      part[o][c2] = s;
    }
    __syncthreads();
    if (tid < N_OUT) {
      float drive = 0.f;
      #pragma unroll
      for (int c2 = 0; c2 < 12; ++c2) drive += part[tid][c2];
      if (mode) drive = SOs[tid] - drive;
      om = TAU*om*(osb ? 0.f : 1.f) + drive;
      const int nos = (om >= THR) ? 1 : 0;
      const float osf = nos ? 1.f : 0.f;
      errs[tid] = osf - label[(size_t)k*N_OUT + tid];
      outs[(size_t)k*N_OUT + tid] = osf;
      osb = nos;
    }
    __syncthreads();

    // L = (err @ W_out) * h'(hm); store into INL (in place); go partial accum
    float d0 = 0.f, d1 = 0.f;
    #pragma unroll
    for (int o = 0; o < N_OUT; ++o) {
      const float e = errs[o];
      d0 += e * sWo[o*N_HID + tid];
      d1 += e * sWo[o*N_HID + 256 + tid];
    }
    const float a0f = fabsf(nhm0 - THR) / THR;
    const float a1f = fabsf(nhm1 - THR) / THR;
    const float ht0 = GAM * fmaxf(0.f, 1.f - a0f);
    const float ht1 = GAM * fmaxf(0.f, 1.f - a1f);
    INL[(size_t)k*N_HID + tid]       = d0 * ht0;
    INL[(size_t)k*N_HID + 256 + tid] = d1 * ht1;

    tout0 = TAU_O*tout0 + (nhs0 ? 1.f : 0.f);
    tout1 = TAU_O*tout1 + (nhs1 ? 1.f : 0.f);
    #pragma unroll
    for (int o = 0; o < N_OUT; ++o) {
      const float e = errs[o];
      go0[o] += e * tout0;
      go1[o] += e * tout1;
    }

    hm0 = nhm0; hm1 = nhm1; hs0 = nhs0; hs1 = nhs1;
    cnt_prev = cnt; mode_prev = mode;
    __syncthreads();
  }
  #pragma unroll
  for (int o = 0; o < N_OUT; ++o) {
    pgo[((size_t)b*N_OUT + o)*N_HID + tid]       = go0[o];
    pgo[((size_t)b*N_OUT + o)*N_HID + 256 + tid] = go1[o];
  }
}

// ---------------- phase C: reverse filter M_s = L_s + tau*M_{s+1}, in place; per-row count ----------------
__global__ void k_mfilter(float* __restrict__ L, int* __restrict__ tmax) {
  const int g = blockIdx.x*256 + threadIdx.x;   // 512 blocks -> (b, r)
  const int b = g >> 9, r = g & 511;
  float m = 0.f;
  int last = -1;
  for (int t = TT - 1; t >= 0; --t) {
    const size_t idx = ((size_t)(b*TT + t))*N_HID + r;
    const float v = L[idx] + TAU*m;
    L[idx] = v;
    m = v;
    if (v != 0.f && last < 0) last = t;         // first hit scanning down == max t
  }
  if (last >= 0) atomicMax(tmax + b, last + 1); // order-independent -> deterministic
}

// ---------------- phase D: gf = 0.1 * sum_k M[k,:]^T x[k,:]  over active (b,t) ----------------
__global__ __launch_bounds__(256) void k_gf(const float* __restrict__ M, const float* __restrict__ x,
                                            const int* __restrict__ tmax,
                                            float* __restrict__ gf) {
  const int lane = threadIdx.x & 63, w = threadIdx.x >> 6;
  const int r  = blockIdx.x*64 + lane;
  const int i0 = blockIdx.y*64 + w*16;
  __shared__ int cnt_sh[BB];
  cnt_sh[threadIdx.x] = tmax[threadIdx.x];
  __syncthreads();
  float acc[16];
  #pragma unroll
  for (int ii = 0; ii < 16; ++ii) acc[ii] = 0.f;
  int xi = i0 + (lane & 15); if (xi > N_IN - 1) xi = N_IN - 1;
  for (int b2 = 0; b2 < BB; ++b2) {
    const int ct = cnt_sh[b2];
    for (int t = 0; t < ct; ++t) {
      const int k = b2*TT + t;
      const float mv = M[(size_t)k*N_HID + r];
      const float xv = x[(size_t)k*N_IN + xi];
      #pragma unroll
      for (int ii = 0; ii < 16; ++ii) acc[ii] += mv * __shfl(xv, ii);
    }
  }
  #pragma unroll
  for (int ii = 0; ii < 16; ++ii) {
    const int i = i0 + ii;
    if (i < N_IN) gf[(size_t)r*N_IN + i] = 0.1f*acc[ii];
  }
}

// ---------------- phase D: gr = 0.1 * sum_k M[k,:]^T hs[k,:] over active (b,t) ----------------
__global__ __launch_bounds__(256) void k_gr(const float* __restrict__ M,
                                            const unsigned long long* __restrict__ hsbits,
                                            const int* __restrict__ tmax,
                                            float* __restrict__ gr) {
  const int lane = threadIdx.x & 63, w = threadIdx.x >> 6;
  const int r  = blockIdx.x*64 + lane;
  const int h0 = blockIdx.y*64 + w*16;
  __shared__ int cnt_sh[BB];
  cnt_sh[threadIdx.x] = tmax[threadIdx.x];
  __syncthreads();
  float acc[16];
  #pragma unroll
  for (int ii = 0; ii < 16; ++ii) acc[ii] = 0.f;
  for (int b2 = 0; b2 < BB; ++b2) {
    const int ct = cnt_sh[b2];
    for (int t = 0; t < ct; ++t) {
      const int k = b2*TT + t;
      const float mv = M[(size_t)k*N_HID + r];
      const unsigned long long word = hsbits[(size_t)k*8 + (h0 >> 6)];
      const int sh = h0 & 63;
      #pragma unroll
      for (int ii = 0; ii < 16; ++ii)
        if ((word >> (sh + ii)) & 1ULL) acc[ii] += mv;
    }
  }
  #pragma unroll
  for (int ii = 0; ii < 16; ++ii)
    gr[(size_t)r*N_HID + h0 + ii] = 0.1f*acc[ii];
}

// ---------------- phase D: go = 0.1 * sum_b pgo[b] ----------------
__global__ void k_go(const float* __restrict__ pgo, float* __restrict__ go) {
  const int g = blockIdx.x*256 + threadIdx.x;   // 40 blocks -> 10240
  float s = 0.f;
  for (int b2 = 0; b2 < BB; ++b2) s += pgo[(size_t)b2*(N_OUT*N_HID) + g];
  go[g] = 0.1f*s;
}

extern "C" void kernel_launch(void* const* d_in, const int* in_sizes, int n_in,
                              void* d_out, int out_size, void* d_ws, size_t ws_size,
                              hipStream_t stream) {
  const float* x     = (const float*)d_in[0];
  const float* label = (const float*)d_in[1];
  const float* W1    = (const float*)d_in[2];
  const float* Wr    = (const float*)d_in[3];
  const float* Wo    = (const float*)d_in[4];

  float* out  = (float*)d_out;
  float* outs = out;                                    // [256][100][20]
  float* gf   = out + 512000;                           // [512][700]
  float* gr   = out + 512000 + 358400;                  // [512][512]
  float* go   = out + 512000 + 358400 + 262144;         // [20][512]

  char* ws = (char*)d_ws;
  size_t off = 0;
  auto alloc = [&](size_t bytes) -> char* {
    char* p = ws + off;
    off += (bytes + 255) & ~(size_t)255;
    return p;
  };
  float* INL  = (float*)alloc((size_t)NK*N_HID*sizeof(float));       // 52.4 MB (IN -> L -> M)
  float* W1T  = (float*)alloc((size_t)N_IN*N_HID*sizeof(float));     // 1.43 MB
  float* WRT  = (float*)alloc((size_t)N_HID*N_HID*sizeof(float));    // 1.05 MB
  float* Srow = (float*)alloc((size_t)N_HID*sizeof(float));
  float* SOs  = (float*)alloc((size_t)N_OUT*sizeof(float));
  unsigned long long* hsb = (unsigned long long*)alloc((size_t)NK*8*sizeof(unsigned long long)); // 1.64 MB
  int* tmax = (int*)alloc((size_t)BB*sizeof(int));
  float* pgo  = (float*)alloc((size_t)BB*N_OUT*N_HID*sizeof(float)); // 10.5 MB

  k_prep_t1<<<(N_IN*N_HID + 255)/256, 256, 0, stream>>>(W1, W1T);
  k_prep_t2<<<(N_HID*N_HID + 255)/256, 256, 0, stream>>>(Wr, WRT);
  k_prep_sums<<<(N_HID + N_OUT + 255)/256, 256, 0, stream>>>(Wr, Wo, Srow, SOs, tmax);
  k_inproj<<<NK/4, 256, 0, stream>>>(x, W1T, INL);
  k_scan<<<BB, 256, 0, stream>>>(INL, label, Wo, WRT, Srow, SOs, hsb, outs, pgo);
  k_mfilter<<<(BB*N_HID)/256, 256, 0, stream>>>(INL, tmax);
  dim3 ggf(8, 11); k_gf<<<ggf, 256, 0, stream>>>(INL, x, tmax, gf);
  dim3 ggr(8, 8);  k_gr<<<ggr, 256, 0, stream>>>(INL, hsb, tmax, gr);
  k_go<<<(N_OUT*N_HID)/256, 256, 0, stream>>>(pgo, go);
}

// Round 3
// 824.951 us; speedup vs baseline: 1.2398x; 1.2330x over previous
//
#include <hip/hip_runtime.h>
#include <cstdint>
#include <cstddef>

#define N_IN  700
#define N_INP 704           // K padded to 32
#define N_HID 512
#define N_OUT 20
#define BB    256
#define TT    100
#define NK    (BB*TT)       // 25600

__device__ __constant__ const float TAU   = 0.6f;
__device__ __constant__ const float TAU_O = 0.6f;
__device__ __constant__ const float THR   = 0.6f;
__device__ __constant__ const float GAM   = 0.3f;

typedef float f32x4 __attribute__((ext_vector_type(4)));
typedef __bf16 bf16x8 __attribute__((ext_vector_type(8)));

__device__ __forceinline__ unsigned short f2bf_rne(float f) {
  uint32_t b = __builtin_bit_cast(uint32_t, f);
  uint32_t r = (b + 0x7FFFu + ((b >> 16) & 1u)) >> 16;
  return (unsigned short)r;
}
__device__ __forceinline__ float bf2f(unsigned short u) {
  uint32_t b = ((uint32_t)u) << 16;
  return __builtin_bit_cast(float, b);
}

// ---------------- prep: W split into hi+lo bf16, [r][i] layout padded to 704 ----------------
__global__ void k_wsplit(const float* __restrict__ W1,
                         unsigned short* __restrict__ WH,
                         unsigned short* __restrict__ WL) {
  int g = blockIdx.x*256 + threadIdx.x;           // 512*88 threads
  if (g >= N_HID*88) return;
  int r = g / 88, c = g - (g/88)*88;
  int ib = c*8;
  unsigned short h[8], l[8];
  #pragma unroll
  for (int j = 0; j < 8; ++j) {
    int i = ib + j;
    float v = (i < N_IN) ? W1[r*N_IN + i] : 0.f;
    unsigned short hh = f2bf_rne(v);
    float res = v - bf2f(hh);
    h[j] = hh;
    l[j] = f2bf_rne(res);
  }
  uint4 hv = make_uint4((uint32_t)h[0] | ((uint32_t)h[1]<<16), (uint32_t)h[2] | ((uint32_t)h[3]<<16),
                        (uint32_t)h[4] | ((uint32_t)h[5]<<16), (uint32_t)h[6] | ((uint32_t)h[7]<<16));
  uint4 lv = make_uint4((uint32_t)l[0] | ((uint32_t)l[1]<<16), (uint32_t)l[2] | ((uint32_t)l[3]<<16),
                        (uint32_t)l[4] | ((uint32_t)l[5]<<16), (uint32_t)l[6] | ((uint32_t)l[7]<<16));
  *(uint4*)(WH + (size_t)r*N_INP + ib) = hv;
  *(uint4*)(WL + (size_t)r*N_INP + ib) = lv;
}

__global__ void k_prep_t2(const float* __restrict__ Wr, float* __restrict__ WRT) {
  int g = blockIdx.x*256 + threadIdx.x;           // g = j*512 + r
  if (g < N_HID*N_HID) {
    int j = g >> 9, r = g & 511;
    WRT[g] = Wr[r*N_HID + j];
  }
}
__global__ void k_prep_sums(const float* __restrict__ Wr, const float* __restrict__ Wo,
                            float* __restrict__ Srow, float* __restrict__ SOs,
                            int* __restrict__ tmax) {
  int g = blockIdx.x*256 + threadIdx.x;
  if (g < N_HID) {
    float s = 0.f;
    for (int j = 0; j < N_HID; ++j) s += Wr[g*N_HID + j];
    Srow[g] = s;
  } else if (g < N_HID + N_OUT) {
    int o = g - N_HID;
    float s = 0.f;
    for (int r = 0; r < N_HID; ++r) s += Wo[o*N_HID + r];
    SOs[o] = s;
  }
  if (g < BB) tmax[g] = 0;
}

// ---------------- phase A: INL = X @ (WH^T + WL^T), MFMA split-bf16, exact to fp32-reorder ----------------
__global__ __launch_bounds__(256) void k_gemm(const float* __restrict__ x,
                                              const unsigned short* __restrict__ WH,
                                              const unsigned short* __restrict__ WL,
                                              float* __restrict__ INL) {
  __shared__ __align__(16) unsigned short sA [128*32];
  __shared__ __align__(16) unsigned short sBh[128*32];
  __shared__ __align__(16) unsigned short sBl[128*32];
  const int tid = threadIdx.x, lane = tid & 63, w = tid >> 6;
  const int k0 = blockIdx.x * 128;                // M
  const int c0 = blockIdx.y * 128;                // N
  const int wr = w >> 1, wc = w & 1;
  const int fr = lane & 15, fk = lane >> 4;

  // staging maps
  const int a_r  = tid >> 1;                      // 0..127
  const int a_cb = (tid & 1) * 16;                // 0 or 16
  const int b_r  = tid >> 2;                      // 0..63 (+64 on pass 2)
  const int b_c  = (tid & 3) * 8;                 // elem offset 0/8/16/24

  const float* xr = x + (size_t)(k0 + a_r) * N_IN;
  const unsigned short* gh = WH + (size_t)(c0 + b_r) * N_INP;
  const unsigned short* gl = WL + (size_t)(c0 + b_r) * N_INP;

  f32x4 acc[4][4];
  #pragma unroll
  for (int m = 0; m < 4; ++m)
    #pragma unroll
    for (int n = 0; n < 4; ++n)
      acc[m][n] = (f32x4){0.f, 0.f, 0.f, 0.f};

  for (int s = 0; s < N_INP/32; ++s) {
    const int i0 = s * 32;
    // ---- stage A (fp32 -> bf16 pack) ----
    float av[16];
    const int col0 = i0 + a_cb;
    if (col0 + 16 <= N_IN) {
      float4 t0 = *(const float4*)(xr + col0);
      float4 t1 = *(const float4*)(xr + col0 + 4);
      float4 t2 = *(const float4*)(xr + col0 + 8);
      float4 t3 = *(const float4*)(xr + col0 + 12);
      av[0]=t0.x; av[1]=t0.y; av[2]=t0.z; av[3]=t0.w;
      av[4]=t1.x; av[5]=t1.y; av[6]=t1.z; av[7]=t1.w;
      av[8]=t2.x; av[9]=t2.y; av[10]=t2.z; av[11]=t2.w;
      av[12]=t3.x; av[13]=t3.y; av[14]=t3.z; av[15]=t3.w;
    } else {
      #pragma unroll
      for (int j = 0; j < 16; ++j) av[j] = (col0 + j < N_IN) ? xr[col0 + j] : 0.f;
    }
    uint32_t us[8];
    #pragma unroll
    for (int p = 0; p < 8; ++p) {
      uint32_t lo = __builtin_bit_cast(uint32_t, av[2*p])   >> 16;   // x in {0,1}: trunc exact
      uint32_t hi = __builtin_bit_cast(uint32_t, av[2*p+1]) & 0xFFFF0000u;
      us[p] = hi | lo;
    }
    *(uint4*)&sA[a_r*32 + a_cb]     = make_uint4(us[0], us[1], us[2], us[3]);
    *(uint4*)&sA[a_r*32 + a_cb + 8] = make_uint4(us[4], us[5], us[6], us[7]);
    // ---- stage B hi/lo (two row passes) ----
    *(uint4*)&sBh[b_r*32 + b_c]      = *(const uint4*)(gh + i0 + b_c);
    *(uint4*)&sBh[(b_r+64)*32 + b_c] = *(const uint4*)(gh + (size_t)64*N_INP + i0 + b_c);
    *(uint4*)&sBl[b_r*32 + b_c]      = *(const uint4*)(gl + i0 + b_c);
    *(uint4*)&sBl[(b_r+64)*32 + b_c] = *(const uint4*)(gl + (size_t)64*N_INP + i0 + b_c);
    __syncthreads();

    bf16x8 a[4], bh[4], bl[4];
    #pragma unroll
    for (int m = 0; m < 4; ++m)
      a[m] = *(const bf16x8*)&sA[(wr*64 + m*16 + fr)*32 + fk*8];
    #pragma unroll
    for (int n = 0; n < 4; ++n) {
      bh[n] = *(const bf16x8*)&sBh[(wc*64 + n*16 + fr)*32 + fk*8];
      bl[n] = *(const bf16x8*)&sBl[(wc*64 + n*16 + fr)*32 + fk*8];
    }
    #pragma unroll
    for (int m = 0; m < 4; ++m)
      #pragma unroll
      for (int n = 0; n < 4; ++n) {
        acc[m][n] = __builtin_amdgcn_mfma_f32_16x16x32_bf16(a[m], bh[n], acc[m][n], 0, 0, 0);
        acc[m][n] = __builtin_amdgcn_mfma_f32_16x16x32_bf16(a[m], bl[n], acc[m][n], 0, 0, 0);
      }
    __syncthreads();
  }
  // epilogue: D[row=(lane>>4)*4+reg][col=lane&15]
  #pragma unroll
  for (int m = 0; m < 4; ++m) {
    #pragma unroll
    for (int n = 0; n < 4; ++n) {
      #pragma unroll
      for (int reg = 0; reg < 4; ++reg) {
        const int row = k0 + wr*64 + m*16 + (lane>>4)*4 + reg;
        const int col = c0 + wc*64 + n*16 + fr;
        INL[(size_t)row*N_HID + col] = acc[m][n][reg];
      }
    }
  }
}

// ---------------- phase B: sequential scan, one batch row per block ----------------
__global__ __launch_bounds__(256) void k_scan(
    float* __restrict__ INL, const float* __restrict__ label,
    const float* __restrict__ Wo, const float* __restrict__ WRT,
    const float* __restrict__ Srow, const float* __restrict__ SOs,
    unsigned long long* __restrict__ hsbits, float* __restrict__ outs,
    float* __restrict__ pgo)
{
  const int b = blockIdx.x, tid = threadIdx.x;
  const int lane = tid & 63, w = tid >> 6;
  const int po = tid / 12, pc2 = tid - po*12;     // part-compute coords (tid<240)
  __shared__ float sWo[N_OUT*N_HID];              // 40 KB
  __shared__ float errs[N_OUT];
  __shared__ int   list[N_HID];
  __shared__ unsigned long long masks[8];
  __shared__ float part[N_OUT][13];

  for (int idx = tid; idx < N_OUT*N_HID; idx += 256) sWo[idx] = Wo[idx];

  float hm0 = 0.f, hm1 = 0.f;
  int   hs0 = 0,   hs1 = 0;
  float om = 0.f;  int osb = 0;
  float tout0 = 0.f, tout1 = 0.f;
  float go0[N_OUT], go1[N_OUT];
  #pragma unroll
  for (int o = 0; o < N_OUT; ++o) { go0[o] = 0.f; go1[o] = 0.f; }
  int cnt_prev = 0, mode_prev = 0;

  const size_t base = (size_t)b*TT;
  float in0 = INL[base*N_HID + tid];
  float in1 = INL[base*N_HID + 256 + tid];
  float lab = (tid < N_OUT) ? label[base*N_OUT + tid] : 0.f;
  const float srow0 = Srow[tid], srow1 = Srow[256 + tid];
  __syncthreads();

  for (int t = 0; t < TT; ++t) {
    const size_t k  = base + t;
    const size_t kn = (t < TT-1) ? (k + 1) : k;   // last-step prefetch discarded
    const float nin0 = INL[kn*N_HID + tid];
    const float nin1 = INL[kn*N_HID + 256 + tid];
    const float nlab = (tid < N_OUT) ? label[kn*N_OUT + tid] : 0.f;

    float s0 = 0.f, s1 = 0.f;
    for (int it = 0; it < cnt_prev; ++it) {
      const int j = list[it];
      s0 += WRT[j*N_HID + tid];
      s1 += WRT[j*N_HID + 256 + tid];
    }
    const float rec0 = mode_prev ? (srow0 - s0) : s0;
    const float rec1 = mode_prev ? (srow1 - s1) : s1;

    const float nhm0 = TAU*hm0*(hs0 ? 0.f : 1.f) + in0 + rec0;
    const float nhm1 = TAU*hm1*(hs1 ? 0.f : 1.f) + in1 + rec1;
    const int nhs0 = (nhm0 >= THR) ? 1 : 0;
    const int nhs1 = (nhm1 >= THR) ? 1 : 0;

    const unsigned long long mA = __ballot(nhs0 != 0);
    const unsigned long long mB = __ballot(nhs1 != 0);
    if (lane == 0) { masks[w] = mA; masks[4 + w] = mB; }
    __syncthreads();                               // (a)

    unsigned long long mk[8];
    #pragma unroll
    for (int q = 0; q < 8; ++q) mk[q] = masks[q];
    if (tid < 8) hsbits[k*8 + tid] = mk[tid];
    int pcs[8];
    #pragma unroll
    for (int q = 0; q < 8; ++q) pcs[q] = (int)__popcll(mk[q]);
    const int ctot = pcs[0]+pcs[1]+pcs[2]+pcs[3]+pcs[4]+pcs[5]+pcs[6]+pcs[7];
    const int mode = (ctot <= 256) ? 0 : 1;
    int pre[8];
    pre[0] = 0;
    #pragma unroll
    for (int q = 1; q < 8; ++q) pre[q] = pre[q-1] + (mode ? 64 - pcs[q-1] : pcs[q-1]);
    const int cnt = pre[7] + (mode ? 64 - pcs[7] : pcs[7]);
    {
      const unsigned long long below = (1ULL << lane) - 1ULL;
      const unsigned long long sm0 = mode ? ~mA : mA;
      const unsigned long long sm1 = mode ? ~mB : mB;
      if (mode ? !nhs0 : nhs0) list[pre[w]     + (int)__popcll(sm0 & below)] = tid;
      if (mode ? !nhs1 : nhs1) list[pre[4 + w] + (int)__popcll(sm1 & below)] = tid + 256;
    }
    __syncthreads();                               // (b)

    if (tid < 240) {
      float s = 0.f;
      for (int it = pc2; it < cnt; it += 12) s += sWo[po*N_HID + list[it]];
      part[po][pc2] = s;
    }
    __syncthreads();                               // (c)

    if (tid < N_OUT) {
      float drive = 0.f;
      #pragma unroll
      for (int c2 = 0; c2 < 12; ++c2) drive += part[tid][c2];
      if (mode) drive = SOs[tid] - drive;
      om = TAU*om*(osb ? 0.f : 1.f) + drive;
      const int nos = (om >= THR) ? 1 : 0;
      const float osf = nos ? 1.f : 0.f;
      errs[tid] = osf - lab;
      outs[k*N_OUT + tid] = osf;
      osb = nos;
    }
    __syncthreads();                               // (d)

    float d0 = 0.f, d1 = 0.f;
    #pragma unroll
    for (int o = 0; o < N_OUT; ++o) {
      const float e = errs[o];
      d0 += e * sWo[o*N_HID + tid];
      d1 += e * sWo[o*N_HID + 256 + tid];
    }
    const float a0f = fabsf(nhm0 - THR) / THR;
    const float a1f = fabsf(nhm1 - THR) / THR;
    const float ht0 = GAM * fmaxf(0.f, 1.f - a0f);
    const float ht1 = GAM * fmaxf(0.f, 1.f - a1f);
    INL[k*N_HID + tid]       = d0 * ht0;
    INL[k*N_HID + 256 + tid] = d1 * ht1;

    tout0 = TAU_O*tout0 + (nhs0 ? 1.f : 0.f);
    tout1 = TAU_O*tout1 + (nhs1 ? 1.f : 0.f);
    #pragma unroll
    for (int o = 0; o < N_OUT; ++o) {
      const float e = errs[o];
      go0[o] += e * tout0;
      go1[o] += e * tout1;
    }

    hm0 = nhm0; hm1 = nhm1; hs0 = nhs0; hs1 = nhs1;
    cnt_prev = cnt; mode_prev = mode;
    in0 = nin0; in1 = nin1; lab = nlab;
  }
  #pragma unroll
  for (int o = 0; o < N_OUT; ++o) {
    pgo[((size_t)b*N_OUT + o)*N_HID + tid]       = go0[o];
    pgo[((size_t)b*N_OUT + o)*N_HID + 256 + tid] = go1[o];
  }
}

// ---------------- phase C: reverse filter M_s = L_s + tau*M_{s+1}, in place; per-row count ----------------
__global__ void k_mfilter(float* __restrict__ L, int* __restrict__ tmax) {
  const int g = blockIdx.x*256 + threadIdx.x;   // 512 blocks -> (b, r)
  const int b = g >> 9, r = g & 511;
  float m = 0.f;
  int last = -1;
  for (int t = TT - 1; t >= 0; --t) {
    const size_t idx = ((size_t)(b*TT + t))*N_HID + r;
    const float v = L[idx] + TAU*m;
    L[idx] = v;
    m = v;
    if (v != 0.f && last < 0) last = t;
  }
  if (last >= 0) atomicMax(tmax + b, last + 1); // order-independent -> deterministic
}

// ---------------- phase D: gf = 0.1 * sum_k M[k,:]^T x[k,:]  over active (b,t) ----------------
__global__ __launch_bounds__(256) void k_gf(const float* __restrict__ M, const float* __restrict__ x,
                                            const int* __restrict__ tmax,
                                            float* __restrict__ gf) {
  const int lane = threadIdx.x & 63, w = threadIdx.x >> 6;
  const int r  = blockIdx.x*64 + lane;
  const int i0 = blockIdx.y*64 + w*16;
  __shared__ int cnt_sh[BB];
  cnt_sh[threadIdx.x] = tmax[threadIdx.x];
  __syncthreads();
  float acc[16];
  #pragma unroll
  for (int ii = 0; ii < 16; ++ii) acc[ii] = 0.f;
  int xi = i0 + (lane & 15); if (xi > N_IN - 1) xi = N_IN - 1;
  for (int b2 = 0; b2 < BB; ++b2) {
    const int ct = cnt_sh[b2];
    for (int t = 0; t < ct; ++t) {
      const int k = b2*TT + t;
      const float mv = M[(size_t)k*N_HID + r];
      const float xv = x[(size_t)k*N_IN + xi];
      #pragma unroll
      for (int ii = 0; ii < 16; ++ii) acc[ii] += mv * __shfl(xv, ii);
    }
  }
  #pragma unroll
  for (int ii = 0; ii < 16; ++ii) {
    const int i = i0 + ii;
    if (i < N_IN) gf[(size_t)r*N_IN + i] = 0.1f*acc[ii];
  }
}

// ---------------- phase D: gr = 0.1 * sum_k M[k,:]^T hs[k,:] over active (b,t) ----------------
__global__ __launch_bounds__(256) void k_gr(const float* __restrict__ M,
                                            const unsigned long long* __restrict__ hsbits,
                                            const int* __restrict__ tmax,
                                            float* __restrict__ gr) {
  const int lane = threadIdx.x & 63, w = threadIdx.x >> 6;
  const int r  = blockIdx.x*64 + lane;
  const int h0 = blockIdx.y*64 + w*16;
  __shared__ int cnt_sh[BB];
  cnt_sh[threadIdx.x] = tmax[threadIdx.x];
  __syncthreads();
  float acc[16];
  #pragma unroll
  for (int ii = 0; ii < 16; ++ii) acc[ii] = 0.f;
  for (int b2 = 0; b2 < BB; ++b2) {
    const int ct = cnt_sh[b2];
    for (int t = 0; t < ct; ++t) {
      const int k = b2*TT + t;
      const float mv = M[(size_t)k*N_HID + r];
      const unsigned long long word = hsbits[(size_t)k*8 + (h0 >> 6)];
      const int sh = h0 & 63;
      #pragma unroll
      for (int ii = 0; ii < 16; ++ii)
        if ((word >> (sh + ii)) & 1ULL) acc[ii] += mv;
    }
  }
  #pragma unroll
  for (int ii = 0; ii < 16; ++ii)
    gr[(size_t)r*N_HID + h0 + ii] = 0.1f*acc[ii];
}

// ---------------- phase D: go = 0.1 * sum_b pgo[b] ----------------
__global__ void k_go(const float* __restrict__ pgo, float* __restrict__ go) {
  const int g = blockIdx.x*256 + threadIdx.x;   // 40 blocks
  float s = 0.f;
  for (int b2 = 0; b2 < BB; ++b2) s += pgo[(size_t)b2*(N_OUT*N_HID) + g];
  go[g] = 0.1f*s;
}

extern "C" void kernel_launch(void* const* d_in, const int* in_sizes, int n_in,
                              void* d_out, int out_size, void* d_ws, size_t ws_size,
                              hipStream_t stream) {
  const float* x     = (const float*)d_in[0];
  const float* label = (const float*)d_in[1];
  const float* W1    = (const float*)d_in[2];
  const float* Wr    = (const float*)d_in[3];
  const float* Wo    = (const float*)d_in[4];

  float* out  = (float*)d_out;
  float* outs = out;                                    // [256][100][20]
  float* gf   = out + 512000;                           // [512][700]
  float* gr   = out + 512000 + 358400;                  // [512][512]
  float* go   = out + 512000 + 358400 + 262144;         // [20][512]

  char* ws = (char*)d_ws;
  size_t off = 0;
  auto alloc = [&](size_t bytes) -> char* {
    char* p = ws + off;
    off += (bytes + 255) & ~(size_t)255;
    return p;
  };
  float* INL  = (float*)alloc((size_t)NK*N_HID*sizeof(float));       // 52.4 MB (IN -> L -> M)
  unsigned short* WH = (unsigned short*)alloc((size_t)N_HID*N_INP*sizeof(unsigned short)); // 0.72 MB
  unsigned short* WL = (unsigned short*)alloc((size_t)N_HID*N_INP*sizeof(unsigned short)); // 0.72 MB
  float* WRT  = (float*)alloc((size_t)N_HID*N_HID*sizeof(float));    // 1.05 MB
  float* Srow = (float*)alloc((size_t)N_HID*sizeof(float));
  float* SOs  = (float*)alloc((size_t)N_OUT*sizeof(float));
  unsigned long long* hsb = (unsigned long long*)alloc((size_t)NK*8*sizeof(unsigned long long)); // 1.64 MB
  int* tmax = (int*)alloc((size_t)BB*sizeof(int));
  float* pgo  = (float*)alloc((size_t)BB*N_OUT*N_HID*sizeof(float)); // 10.5 MB

  k_wsplit<<<(N_HID*88 + 255)/256, 256, 0, stream>>>(W1, WH, WL);
  k_prep_t2<<<(N_HID*N_HID + 255)/256, 256, 0, stream>>>(Wr, WRT);
  k_prep_sums<<<(N_HID + N_OUT + 255)/256, 256, 0, stream>>>(Wr, Wo, Srow, SOs, tmax);
  dim3 gg(NK/128, N_HID/128);
  k_gemm<<<gg, 256, 0, stream>>>(x, WH, WL, INL);
  k_scan<<<BB, 256, 0, stream>>>(INL, label, Wo, WRT, Srow, SOs, hsb, outs, pgo);
  k_mfilter<<<(BB*N_HID)/256, 256, 0, stream>>>(INL, tmax);
  dim3 ggf(8, 11); k_gf<<<ggf, 256, 0, stream>>>(INL, x, tmax, gf);
  dim3 ggr(8, 8);  k_gr<<<ggr, 256, 0, stream>>>(INL, hsb, tmax, gr);
  k_go<<<(N_OUT*N_HID)/256, 256, 0, stream>>>(pgo, go);
}

// Round 4
// 499.652 us; speedup vs baseline: 2.0470x; 1.6510x over previous
//
#include <hip/hip_runtime.h>
#include <cstdint>
#include <cstddef>

#define N_IN  700
#define N_INP 704           // K padded to 32
#define N_HID 512
#define N_OUT 20
#define BB    256
#define TT    100
#define NK    (BB*TT)       // 25600
#define NCH   8             // split-k chunks for gf/gr

__device__ __constant__ const float TAU   = 0.6f;
__device__ __constant__ const float TAU_O = 0.6f;
__device__ __constant__ const float THR   = 0.6f;
__device__ __constant__ const float GAM   = 0.3f;

typedef float f32x4 __attribute__((ext_vector_type(4)));
typedef __bf16 bf16x8 __attribute__((ext_vector_type(8)));

__device__ __forceinline__ unsigned short f2bf_rne(float f) {
  uint32_t b = __builtin_bit_cast(uint32_t, f);
  uint32_t r = (b + 0x7FFFu + ((b >> 16) & 1u)) >> 16;
  return (unsigned short)r;
}
__device__ __forceinline__ float bf2f(unsigned short u) {
  uint32_t b = ((uint32_t)u) << 16;
  return __builtin_bit_cast(float, b);
}

// ---------------- prep: W split into hi+lo bf16, [r][i] layout padded to 704 ----------------
__global__ void k_wsplit(const float* __restrict__ W1,
                         unsigned short* __restrict__ WH,
                         unsigned short* __restrict__ WL) {
  int g = blockIdx.x*256 + threadIdx.x;           // 512*88 threads
  if (g >= N_HID*88) return;
  int r = g / 88, c = g - (g/88)*88;
  int ib = c*8;
  unsigned short h[8], l[8];
  #pragma unroll
  for (int j = 0; j < 8; ++j) {
    int i = ib + j;
    float v = (i < N_IN) ? W1[r*N_IN + i] : 0.f;
    unsigned short hh = f2bf_rne(v);
    float res = v - bf2f(hh);
    h[j] = hh;
    l[j] = f2bf_rne(res);
  }
  uint4 hv = make_uint4((uint32_t)h[0] | ((uint32_t)h[1]<<16), (uint32_t)h[2] | ((uint32_t)h[3]<<16),
                        (uint32_t)h[4] | ((uint32_t)h[5]<<16), (uint32_t)h[6] | ((uint32_t)h[7]<<16));
  uint4 lv = make_uint4((uint32_t)l[0] | ((uint32_t)l[1]<<16), (uint32_t)l[2] | ((uint32_t)l[3]<<16),
                        (uint32_t)l[4] | ((uint32_t)l[5]<<16), (uint32_t)l[6] | ((uint32_t)l[7]<<16));
  *(uint4*)(WH + (size_t)r*N_INP + ib) = hv;
  *(uint4*)(WL + (size_t)r*N_INP + ib) = lv;
}

__global__ void k_prep_t2(const float* __restrict__ Wr, float* __restrict__ WRT) {
  int g = blockIdx.x*256 + threadIdx.x;           // g = j*512 + r
  if (g < N_HID*N_HID) {
    int j = g >> 9, r = g & 511;
    WRT[g] = Wr[r*N_HID + j];
  }
}
__global__ void k_prep_sums(const float* __restrict__ Wr, const float* __restrict__ Wo,
                            float* __restrict__ Srow, float* __restrict__ SOs,
                            int* __restrict__ tmax) {
  int g = blockIdx.x*256 + threadIdx.x;
  if (g < N_HID) {
    float s = 0.f;
    for (int j = 0; j < N_HID; ++j) s += Wr[g*N_HID + j];
    Srow[g] = s;
  } else if (g < N_HID + N_OUT) {
    int o = g - N_HID;
    float s = 0.f;
    for (int r = 0; r < N_HID; ++r) s += Wo[o*N_HID + r];
    SOs[o] = s;
  }
  if (g < BB) tmax[g] = 0;
}

// ---------------- phase A: INL = X @ (WH^T + WL^T), MFMA split-bf16 ----------------
__global__ __launch_bounds__(256) void k_gemm(const float* __restrict__ x,
                                              const unsigned short* __restrict__ WH,
                                              const unsigned short* __restrict__ WL,
                                              float* __restrict__ INL) {
  __shared__ __align__(16) unsigned short sA [128*32];
  __shared__ __align__(16) unsigned short sBh[128*32];
  __shared__ __align__(16) unsigned short sBl[128*32];
  const int tid = threadIdx.x, lane = tid & 63, w = tid >> 6;
  const int k0 = blockIdx.x * 128;                // M
  const int c0 = blockIdx.y * 128;                // N
  const int wr = w >> 1, wc = w & 1;
  const int fr = lane & 15, fk = lane >> 4;

  const int a_r  = tid >> 1;
  const int a_cb = (tid & 1) * 16;
  const int b_r  = tid >> 2;
  const int b_c  = (tid & 3) * 8;

  const float* xr = x + (size_t)(k0 + a_r) * N_IN;
  const unsigned short* gh = WH + (size_t)(c0 + b_r) * N_INP;
  const unsigned short* gl = WL + (size_t)(c0 + b_r) * N_INP;

  f32x4 acc[4][4];
  #pragma unroll
  for (int m = 0; m < 4; ++m)
    #pragma unroll
    for (int n = 0; n < 4; ++n)
      acc[m][n] = (f32x4){0.f, 0.f, 0.f, 0.f};

  for (int s = 0; s < N_INP/32; ++s) {
    const int i0 = s * 32;
    float av[16];
    const int col0 = i0 + a_cb;
    if (col0 + 16 <= N_IN) {
      float4 t0 = *(const float4*)(xr + col0);
      float4 t1 = *(const float4*)(xr + col0 + 4);
      float4 t2 = *(const float4*)(xr + col0 + 8);
      float4 t3 = *(const float4*)(xr + col0 + 12);
      av[0]=t0.x; av[1]=t0.y; av[2]=t0.z; av[3]=t0.w;
      av[4]=t1.x; av[5]=t1.y; av[6]=t1.z; av[7]=t1.w;
      av[8]=t2.x; av[9]=t2.y; av[10]=t2.z; av[11]=t2.w;
      av[12]=t3.x; av[13]=t3.y; av[14]=t3.z; av[15]=t3.w;
    } else {
      #pragma unroll
      for (int j = 0; j < 16; ++j) av[j] = (col0 + j < N_IN) ? xr[col0 + j] : 0.f;
    }
    uint32_t us[8];
    #pragma unroll
    for (int p = 0; p < 8; ++p) {
      uint32_t lo = __builtin_bit_cast(uint32_t, av[2*p])   >> 16;   // x in {0,1}: trunc exact
      uint32_t hi = __builtin_bit_cast(uint32_t, av[2*p+1]) & 0xFFFF0000u;
      us[p] = hi | lo;
    }
    *(uint4*)&sA[a_r*32 + a_cb]     = make_uint4(us[0], us[1], us[2], us[3]);
    *(uint4*)&sA[a_r*32 + a_cb + 8] = make_uint4(us[4], us[5], us[6], us[7]);
    *(uint4*)&sBh[b_r*32 + b_c]      = *(const uint4*)(gh + i0 + b_c);
    *(uint4*)&sBh[(b_r+64)*32 + b_c] = *(const uint4*)(gh + (size_t)64*N_INP + i0 + b_c);
    *(uint4*)&sBl[b_r*32 + b_c]      = *(const uint4*)(gl + i0 + b_c);
    *(uint4*)&sBl[(b_r+64)*32 + b_c] = *(const uint4*)(gl + (size_t)64*N_INP + i0 + b_c);
    __syncthreads();

    bf16x8 a[4], bh[4], bl[4];
    #pragma unroll
    for (int m = 0; m < 4; ++m)
      a[m] = *(const bf16x8*)&sA[(wr*64 + m*16 + fr)*32 + fk*8];
    #pragma unroll
    for (int n = 0; n < 4; ++n) {
      bh[n] = *(const bf16x8*)&sBh[(wc*64 + n*16 + fr)*32 + fk*8];
      bl[n] = *(const bf16x8*)&sBl[(wc*64 + n*16 + fr)*32 + fk*8];
    }
    #pragma unroll
    for (int m = 0; m < 4; ++m)
      #pragma unroll
      for (int n = 0; n < 4; ++n) {
        acc[m][n] = __builtin_amdgcn_mfma_f32_16x16x32_bf16(a[m], bh[n], acc[m][n], 0, 0, 0);
        acc[m][n] = __builtin_amdgcn_mfma_f32_16x16x32_bf16(a[m], bl[n], acc[m][n], 0, 0, 0);
      }
    __syncthreads();
  }
  #pragma unroll
  for (int m = 0; m < 4; ++m) {
    #pragma unroll
    for (int n = 0; n < 4; ++n) {
      #pragma unroll
      for (int reg = 0; reg < 4; ++reg) {
        const int row = k0 + wr*64 + m*16 + (lane>>4)*4 + reg;
        const int col = c0 + wc*64 + n*16 + fr;
        INL[(size_t)row*N_HID + col] = acc[m][n][reg];
      }
    }
  }
}

// ---------------- phase B: sequential scan, one batch row per block ----------------
__global__ __launch_bounds__(256) void k_scan(
    float* __restrict__ INL, const float* __restrict__ label,
    const float* __restrict__ Wo, const float* __restrict__ WRT,
    const float* __restrict__ Srow, const float* __restrict__ SOs,
    unsigned long long* __restrict__ hsbits, float* __restrict__ outs,
    float* __restrict__ pgo)
{
  const int b = blockIdx.x, tid = threadIdx.x;
  const int lane = tid & 63, w = tid >> 6;
  const int po = tid / 12, pc2 = tid - po*12;
  __shared__ float sWo[N_OUT*N_HID];
  __shared__ float errs[N_OUT];
  __shared__ int   list[N_HID];
  __shared__ unsigned long long masks[8];
  __shared__ float part[N_OUT][13];

  for (int idx = tid; idx < N_OUT*N_HID; idx += 256) sWo[idx] = Wo[idx];

  float hm0 = 0.f, hm1 = 0.f;
  int   hs0 = 0,   hs1 = 0;
  float om = 0.f;  int osb = 0;
  float tout0 = 0.f, tout1 = 0.f;
  float go0[N_OUT], go1[N_OUT];
  #pragma unroll
  for (int o = 0; o < N_OUT; ++o) { go0[o] = 0.f; go1[o] = 0.f; }
  int cnt_prev = 0, mode_prev = 0;

  const size_t base = (size_t)b*TT;
  float in0 = INL[base*N_HID + tid];
  float in1 = INL[base*N_HID + 256 + tid];
  float lab = (tid < N_OUT) ? label[base*N_OUT + tid] : 0.f;
  const float srow0 = Srow[tid], srow1 = Srow[256 + tid];
  __syncthreads();

  for (int t = 0; t < TT; ++t) {
    const size_t k  = base + t;
    const size_t kn = (t < TT-1) ? (k + 1) : k;
    const float nin0 = INL[kn*N_HID + tid];
    const float nin1 = INL[kn*N_HID + 256 + tid];
    const float nlab = (tid < N_OUT) ? label[kn*N_OUT + tid] : 0.f;

    float s0 = 0.f, s1 = 0.f;
    for (int it = 0; it < cnt_prev; ++it) {
      const int j = list[it];
      s0 += WRT[j*N_HID + tid];
      s1 += WRT[j*N_HID + 256 + tid];
    }
    const float rec0 = mode_prev ? (srow0 - s0) : s0;
    const float rec1 = mode_prev ? (srow1 - s1) : s1;

    const float nhm0 = TAU*hm0*(hs0 ? 0.f : 1.f) + in0 + rec0;
    const float nhm1 = TAU*hm1*(hs1 ? 0.f : 1.f) + in1 + rec1;
    const int nhs0 = (nhm0 >= THR) ? 1 : 0;
    const int nhs1 = (nhm1 >= THR) ? 1 : 0;

    const unsigned long long mA = __ballot(nhs0 != 0);
    const unsigned long long mB = __ballot(nhs1 != 0);
    if (lane == 0) { masks[w] = mA; masks[4 + w] = mB; }
    __syncthreads();                               // (a)

    unsigned long long mk[8];
    #pragma unroll
    for (int q = 0; q < 8; ++q) mk[q] = masks[q];
    if (tid < 8) hsbits[k*8 + tid] = mk[tid];
    int pcs[8];
    #pragma unroll
    for (int q = 0; q < 8; ++q) pcs[q] = (int)__popcll(mk[q]);
    const int ctot = pcs[0]+pcs[1]+pcs[2]+pcs[3]+pcs[4]+pcs[5]+pcs[6]+pcs[7];
    const int mode = (ctot <= 256) ? 0 : 1;
    int pre[8];
    pre[0] = 0;
    #pragma unroll
    for (int q = 1; q < 8; ++q) pre[q] = pre[q-1] + (mode ? 64 - pcs[q-1] : pcs[q-1]);
    const int cnt = pre[7] + (mode ? 64 - pcs[7] : pcs[7]);
    {
      const unsigned long long below = (1ULL << lane) - 1ULL;
      const unsigned long long sm0 = mode ? ~mA : mA;
      const unsigned long long sm1 = mode ? ~mB : mB;
      if (mode ? !nhs0 : nhs0) list[pre[w]     + (int)__popcll(sm0 & below)] = tid;
      if (mode ? !nhs1 : nhs1) list[pre[4 + w] + (int)__popcll(sm1 & below)] = tid + 256;
    }
    __syncthreads();                               // (b)

    if (tid < 240) {
      float s = 0.f;
      for (int it = pc2; it < cnt; it += 12) s += sWo[po*N_HID + list[it]];
      part[po][pc2] = s;
    }
    __syncthreads();                               // (c)

    if (tid < N_OUT) {
      float drive = 0.f;
      #pragma unroll
      for (int c2 = 0; c2 < 12; ++c2) drive += part[tid][c2];
      if (mode) drive = SOs[tid] - drive;
      om = TAU*om*(osb ? 0.f : 1.f) + drive;
      const int nos = (om >= THR) ? 1 : 0;
      const float osf = nos ? 1.f : 0.f;
      errs[tid] = osf - lab;
      outs[k*N_OUT + tid] = osf;
      osb = nos;
    }
    __syncthreads();                               // (d)

    float d0 = 0.f, d1 = 0.f;
    #pragma unroll
    for (int o = 0; o < N_OUT; ++o) {
      const float e = errs[o];
      d0 += e * sWo[o*N_HID + tid];
      d1 += e * sWo[o*N_HID + 256 + tid];
    }
    const float a0f = fabsf(nhm0 - THR) / THR;
    const float a1f = fabsf(nhm1 - THR) / THR;
    const float ht0 = GAM * fmaxf(0.f, 1.f - a0f);
    const float ht1 = GAM * fmaxf(0.f, 1.f - a1f);
    INL[k*N_HID + tid]       = d0 * ht0;
    INL[k*N_HID + 256 + tid] = d1 * ht1;

    tout0 = TAU_O*tout0 + (nhs0 ? 1.f : 0.f);
    tout1 = TAU_O*tout1 + (nhs1 ? 1.f : 0.f);
    #pragma unroll
    for (int o = 0; o < N_OUT; ++o) {
      const float e = errs[o];
      go0[o] += e * tout0;
      go1[o] += e * tout1;
    }

    hm0 = nhm0; hm1 = nhm1; hs0 = nhs0; hs1 = nhs1;
    cnt_prev = cnt; mode_prev = mode;
    in0 = nin0; in1 = nin1; lab = nlab;
  }
  #pragma unroll
  for (int o = 0; o < N_OUT; ++o) {
    pgo[((size_t)b*N_OUT + o)*N_HID + tid]       = go0[o];
    pgo[((size_t)b*N_OUT + o)*N_HID + 256 + tid] = go1[o];
  }
}

// ---------------- phase C: reverse filter M_s = L_s + tau*M_{s+1}, in place; per-row count ----------------
__global__ void k_mfilter(float* __restrict__ L, int* __restrict__ tmax) {
  const int g = blockIdx.x*256 + threadIdx.x;   // 512 blocks -> (b, r)
  const int b = g >> 9, r = g & 511;
  float m = 0.f;
  int last = -1;
  for (int t = TT - 1; t >= 0; --t) {
    const size_t idx = ((size_t)(b*TT + t))*N_HID + r;
    const float v = L[idx] + TAU*m;
    L[idx] = v;
    m = v;
    if (v != 0.f && last < 0) last = t;
  }
  if (last >= 0) atomicMax(tmax + b, last + 1);
}

// ---------------- phase D: go = 0.1 * sum_b pgo[b]  (runs EARLY to free pgo region) ----------------
__global__ void k_go(const float* __restrict__ pgo, float* __restrict__ go) {
  const int g = blockIdx.x*256 + threadIdx.x;
  float s = 0.f;
  for (int b2 = 0; b2 < BB; ++b2) s += pgo[(size_t)b2*(N_OUT*N_HID) + g];
  go[g] = 0.1f*s;
}

// ---------------- phase D: gf partials over b-chunks ----------------
__global__ __launch_bounds__(256) void k_gf(const float* __restrict__ M, const float* __restrict__ x,
                                            const int* __restrict__ tmax,
                                            float* __restrict__ gfp) {
  const int lane = threadIdx.x & 63, w = threadIdx.x >> 6;
  const int r  = blockIdx.x*64 + lane;
  const int i0 = blockIdx.y*64 + w*16;
  const int ch = blockIdx.z;
  const int b_lo = ch * (BB/NCH);
  __shared__ int cnt_sh[BB/NCH];
  if (threadIdx.x < BB/NCH) cnt_sh[threadIdx.x] = tmax[b_lo + threadIdx.x];
  __syncthreads();
  float acc[16];
  #pragma unroll
  for (int ii = 0; ii < 16; ++ii) acc[ii] = 0.f;
  int xi = i0 + (lane & 15); if (xi > N_IN - 1) xi = N_IN - 1;
  for (int bi = 0; bi < BB/NCH; ++bi) {
    const int ct = cnt_sh[bi];
    if (ct == 0) continue;
    const size_t kb = (size_t)(b_lo + bi)*TT;
    float mv = M[kb*N_HID + r];
    float xv = x[kb*N_IN + xi];
    for (int t = 0; t < ct; ++t) {
      float mv_n = 0.f, xv_n = 0.f;
      if (t + 1 < ct) {
        mv_n = M[(kb + t + 1)*N_HID + r];
        xv_n = x[(kb + t + 1)*N_IN + xi];
      }
      #pragma unroll
      for (int ii = 0; ii < 16; ++ii) acc[ii] += mv * __shfl(xv, ii);
      mv = mv_n; xv = xv_n;
    }
  }
  #pragma unroll
  for (int ii = 0; ii < 16; ++ii) {
    const int i = i0 + ii;
    if (i < N_IN) gfp[(size_t)ch*(N_HID*N_IN) + (size_t)r*N_IN + i] = acc[ii];
  }
}

// ---------------- phase D: gr partials over b-chunks ----------------
__global__ __launch_bounds__(256) void k_gr(const float* __restrict__ M,
                                            const unsigned long long* __restrict__ hsbits,
                                            const int* __restrict__ tmax,
                                            float* __restrict__ grp) {
  const int lane = threadIdx.x & 63, w = threadIdx.x >> 6;
  const int r  = blockIdx.x*64 + lane;
  const int h0 = blockIdx.y*64 + w*16;
  const int ch = blockIdx.z;
  const int b_lo = ch * (BB/NCH);
  __shared__ int cnt_sh[BB/NCH];
  if (threadIdx.x < BB/NCH) cnt_sh[threadIdx.x] = tmax[b_lo + threadIdx.x];
  __syncthreads();
  float acc[16];
  #pragma unroll
  for (int ii = 0; ii < 16; ++ii) acc[ii] = 0.f;
  const int hw = h0 >> 6, sh = h0 & 63;
  for (int bi = 0; bi < BB/NCH; ++bi) {
    const int ct = cnt_sh[bi];
    if (ct == 0) continue;
    const size_t kb = (size_t)(b_lo + bi)*TT;
    float mv = M[kb*N_HID + r];
    unsigned long long word = hsbits[kb*8 + hw];
    for (int t = 0; t < ct; ++t) {
      float mv_n = 0.f; unsigned long long word_n = 0ULL;
      if (t + 1 < ct) {
        mv_n = M[(kb + t + 1)*N_HID + r];
        word_n = hsbits[(kb + t + 1)*8 + hw];
      }
      #pragma unroll
      for (int ii = 0; ii < 16; ++ii)
        if ((word >> (sh + ii)) & 1ULL) acc[ii] += mv;
      mv = mv_n; word = word_n;
    }
  }
  #pragma unroll
  for (int ii = 0; ii < 16; ++ii)
    grp[(size_t)ch*(N_HID*N_HID) + (size_t)r*N_HID + h0 + ii] = acc[ii];
}

// ---------------- phase D: deterministic partial reductions ----------------
__global__ void k_gfred(const float* __restrict__ gfp, float* __restrict__ gf) {
  const int g = blockIdx.x*256 + threadIdx.x;
  if (g < N_HID*N_IN) {
    float s = 0.f;
    #pragma unroll
    for (int c = 0; c < NCH; ++c) s += gfp[(size_t)c*(N_HID*N_IN) + g];
    gf[g] = 0.1f*s;
  }
}
__global__ void k_grred(const float* __restrict__ grp, float* __restrict__ gr) {
  const int g = blockIdx.x*256 + threadIdx.x;
  if (g < N_HID*N_HID) {
    float s = 0.f;
    #pragma unroll
    for (int c = 0; c < NCH; ++c) s += grp[(size_t)c*(N_HID*N_HID) + g];
    gr[g] = 0.1f*s;
  }
}

extern "C" void kernel_launch(void* const* d_in, const int* in_sizes, int n_in,
                              void* d_out, int out_size, void* d_ws, size_t ws_size,
                              hipStream_t stream) {
  const float* x     = (const float*)d_in[0];
  const float* label = (const float*)d_in[1];
  const float* W1    = (const float*)d_in[2];
  const float* Wr    = (const float*)d_in[3];
  const float* Wo    = (const float*)d_in[4];

  float* out  = (float*)d_out;
  float* outs = out;                                    // [256][100][20]
  float* gf   = out + 512000;                           // [512][700]
  float* gr   = out + 512000 + 358400;                  // [512][512]
  float* go   = out + 512000 + 358400 + 262144;         // [20][512]

  char* ws = (char*)d_ws;
  size_t off = 0;
  auto alloc = [&](size_t bytes) -> char* {
    char* p = ws + off;
    off += (bytes + 255) & ~(size_t)255;
    return p;
  };
  float* INL = (float*)alloc((size_t)NK*N_HID*sizeof(float));                    // 52.43 MB
  unsigned long long* hsb = (unsigned long long*)alloc((size_t)NK*8*sizeof(unsigned long long)); // 1.64 MB
  int* tmax = (int*)alloc((size_t)BB*sizeof(int));
  char* uni = alloc((size_t)20971520);                                           // 20 MB union region

  // early residents of uni (dead after k_go)
  unsigned short* WH = (unsigned short*)(uni);                                   // 0.72 MB
  unsigned short* WL = (unsigned short*)(uni + 720896);                          // 0.72 MB
  float* WRT  = (float*)(uni + 2*720896);                                        // 1.05 MB
  float* Srow = (float*)(uni + 2*720896 + 1048576);
  float* SOs  = (float*)(uni + 2*720896 + 1048576 + 2048);
  float* pgo  = (float*)(uni + 2*720896 + 1048576 + 4096);                       // 10.49 MB
  // late residents of uni (written only after k_go has consumed pgo)
  float* gfp  = (float*)(uni);                                                   // 11.47 MB
  float* grp  = (float*)(uni + (size_t)NCH*N_HID*N_IN*sizeof(float));            // 8.39 MB

  k_wsplit<<<(N_HID*88 + 255)/256, 256, 0, stream>>>(W1, WH, WL);
  k_prep_t2<<<(N_HID*N_HID + 255)/256, 256, 0, stream>>>(Wr, WRT);
  k_prep_sums<<<(N_HID + N_OUT + 255)/256, 256, 0, stream>>>(Wr, Wo, Srow, SOs, tmax);
  dim3 gg(NK/128, N_HID/128);
  k_gemm<<<gg, 256, 0, stream>>>(x, WH, WL, INL);
  k_scan<<<BB, 256, 0, stream>>>(INL, label, Wo, WRT, Srow, SOs, hsb, outs, pgo);
  k_mfilter<<<(BB*N_HID)/256, 256, 0, stream>>>(INL, tmax);
  k_go<<<(N_OUT*N_HID)/256, 256, 0, stream>>>(pgo, go);
  dim3 ggf(8, 11, NCH); k_gf<<<ggf, 256, 0, stream>>>(INL, x, tmax, gfp);
  dim3 ggr(8, 8, NCH);  k_gr<<<ggr, 256, 0, stream>>>(INL, hsb, tmax, grp);
  k_gfred<<<(N_HID*N_IN + 255)/256, 256, 0, stream>>>(gfp, gf);
  k_grred<<<(N_HID*N_HID + 255)/256, 256, 0, stream>>>(grp, gr);
}